// Round 13
// baseline (2290.281 us; speedup 1.0000x reference)
//
#include <hip/hip_runtime.h>
#include <math.h>

#define BATCH 256
#define TT    784
#define HH    512
#define NCLS  10

#define NB 64          // batch groups
#define NJ 4           // blocks per group; block owns 128 cols
#define MB 4           // batch rows per group
#define HJ 128         // output cols per block
#define NT 512         // threads per block (8 waves, 2/SIMD)

typedef unsigned long long ull;
typedef unsigned int uint32;

#define AL(p)    __hip_atomic_load((p), __ATOMIC_RELAXED, __HIP_MEMORY_SCOPE_AGENT)
#define AS(p, v) __hip_atomic_store((p), (v), __ATOMIC_RELAXED, __HIP_MEMORY_SCOPE_AGENT)

// R0-R12 LESSONS (journal):
//  * R12 win (-26%): self-validating (value,tag) 8B publishes killed 2 of 3
//    L2 round-trips (drain + flag). WRITE_SIZE 451->803 MB confirmed active.
//  * VALUBusy on gfx950 is ~2x inflated (gfx94x derived formula, SIMD-16
//    assumption): R12's "80%" is ~40% real. Remaining ~3300 cyc/step is
//    non-VALU: barriers, publish->detect latency, per-row LDS stalls.
//  * THIS ROUND: delete barrier C. (a) pbuf parity-double-buffered: pack(t+2)
//    WAR on half p is covered by B(t+1). (b) ALL waves poll tags, incl.
//    own-block (drop own-slice hp shortcut): hp hazards become wave-private
//    (wave w stages+reads only cols [64w,+64)). R7's own-via-global loss was
//    the drain+flag protocol; with tags an own poll is a cheap L2 hit.
//    Deadlock-free: monotone tag chain. hbufU WAR: overwrite (tag t+3) is
//    gated through sibling B(t+1)/B(t+2) barriers -> all t+1 reads precede.
//  * R10 coherence rule stands: cross-CU reads MUST bypass L1 (AL = sc0).
//
// d_ws layout:
//   [8192, 8192+2MB) : hbufU ull[2][BATCH][HH] — (tag<<32)|float_bits,
//                      agent-relaxed. Tags zeroed by hipMemsetAsync each
//                      launch (resets between bench iterations).

// Opaque register pin: weights become outputs of a volatile asm — cannot be
// rematerialized or sunk into the loop.
#define PIN(V) asm volatile("" : "+v"((V).x), "+v"((V).y), "+v"((V).z), "+v"((V).w))

__global__ __launch_bounds__(NT)
__attribute__((amdgpu_waves_per_eu(2, 2)))
void rnn_main_kernel(
    const float* __restrict__ inputs, const int* __restrict__ order,
    const float* __restrict__ W_ih, const float* __restrict__ b_ih,
    const float* __restrict__ W_hh, const float* __restrict__ b_hh,
    ull* __restrict__ hbufU)
{
    __shared__ float hp[MB * HH];            // 8 KB : h tile (wave-private cols)
    __shared__ float pbuf[2 * 16 * MB * HJ]; // 64 KB: DOUBLE-BUFFERED partials
    __shared__ float xall[TT * MB];          // 12.25 KB: inputs[b][order[t]]
    __shared__ float wih_s[HJ];
    __shared__ float bias_s[HJ];
    // total ~85.3 KB -> 1 block/CU

    const int tid   = threadIdx.x;
    const int blk   = blockIdx.x;
    const int bb    = blk & (NB - 1);        // group; members blk=bb+64g -> same XCD under %8
    const int jjg   = blk >> 6;              // producer id 0..3: cols [jjg*128, +128)
    const int jbase = jjg * HJ;
    const int bbase = bb * MB;
    const int j   = tid & 31;                // base col lane: cols {j, j+32, j+64, j+96}
    const int kg  = tid >> 5;                // k-chunk 0..15 (32 k each)
    const int w   = tid >> 6;                // wave: k-window [64w,+64)
    const int l   = tid & 63;

    // ---- W_hh slice in NAMED registers: 4 cols x 32 k = 32 float4
    //      (live in the unified VGPR/AGPR file; VALU reads them directly)
    const float4* wpa = (const float4*)(W_hh + (size_t)(jbase + j +  0) * HH + kg * 32);
    const float4* wpb = (const float4*)(W_hh + (size_t)(jbase + j + 32) * HH + kg * 32);
    const float4* wpc = (const float4*)(W_hh + (size_t)(jbase + j + 64) * HH + kg * 32);
    const float4* wpd = (const float4*)(W_hh + (size_t)(jbase + j + 96) * HH + kg * 32);
    float4 wa0 = wpa[0], wa1 = wpa[1], wa2 = wpa[2], wa3 = wpa[3];
    float4 wa4 = wpa[4], wa5 = wpa[5], wa6 = wpa[6], wa7 = wpa[7];
    float4 wb0 = wpb[0], wb1 = wpb[1], wb2 = wpb[2], wb3 = wpb[3];
    float4 wb4 = wpb[4], wb5 = wpb[5], wb6 = wpb[6], wb7 = wpb[7];
    float4 wc0 = wpc[0], wc1 = wpc[1], wc2 = wpc[2], wc3 = wpc[3];
    float4 wc4 = wpc[4], wc5 = wpc[5], wc6 = wpc[6], wc7 = wpc[7];
    float4 wd0 = wpd[0], wd1 = wpd[1], wd2 = wpd[2], wd3 = wpd[3];
    float4 wd4 = wpd[4], wd5 = wpd[5], wd6 = wpd[6], wd7 = wpd[7];

    PIN(wa0); PIN(wa1); PIN(wa2); PIN(wa3);
    PIN(wa4); PIN(wa5); PIN(wa6); PIN(wa7);
    PIN(wb0); PIN(wb1); PIN(wb2); PIN(wb3);
    PIN(wb4); PIN(wb5); PIN(wb6); PIN(wb7);
    PIN(wc0); PIN(wc1); PIN(wc2); PIN(wc3);
    PIN(wc4); PIN(wc5); PIN(wc6); PIN(wc7);
    PIN(wd0); PIN(wd1); PIN(wd2); PIN(wd3);
    PIN(wd4); PIN(wd5); PIN(wd6); PIN(wd7);

    if (tid < HJ) {
        wih_s[tid]  = W_ih[jbase + tid];
        bias_s[tid] = b_ih[jbase + tid] + b_hh[jbase + tid];
    }
    for (int idx = tid; idx < TT * MB; idx += NT) {
        const int t = idx >> 2;
        const int b = idx & (MB - 1);
        xall[idx] = inputs[(size_t)(bbase + b) * TT + order[t]];
    }
    ((float4*)hp)[tid] = make_float4(0.f, 0.f, 0.f, 0.f);   // h_0 = 0 (8 KB)
    __syncthreads();

    const float4* hp4 = (const float4*)hp;

    for (int t = 0; t < TT; ++t) {
        const int p = t & 1;
        float* Pp = pbuf + (p << 13);        // this step's 8192-float pbuf half

        // ---- per-wave gate+stage fused: each lane polls ITS OWN 4 pair-words
        //      (one per batch row at col w*64+l). Tag match => value already
        //      in-register; 4 ds_writes finish the stage. ALL waves poll —
        //      own-block elements are same-XCD L2 hits; hp is wave-private.
        if (t > 0) {
            const uint32 tg = (uint32)t;
            const ull* src = hbufU + (size_t)p * BATCH * HH
                             + (size_t)bbase * HH + w * 64 + l;
            ull u0, u1, u2, u3;
            for (;;) {
                u0 = AL(src);            u1 = AL(src + HH);
                u2 = AL(src + 2 * HH);   u3 = AL(src + 3 * HH);
                const int ok = ((uint32)(u0 >> 32) >= tg) & ((uint32)(u1 >> 32) >= tg)
                             & ((uint32)(u2 >> 32) >= tg) & ((uint32)(u3 >> 32) >= tg);
                if (__all(ok)) break;
            }
            hp[0 * HH + w * 64 + l] = __uint_as_float((uint32)u0);
            hp[1 * HH + w * 64 + l] = __uint_as_float((uint32)u1);
            hp[2 * HH + w * 64 + l] = __uint_as_float((uint32)u2);
            hp[3 * HH + w * 64 + l] = __uint_as_float((uint32)u3);
        }
        // intra-wave LDS RAW (wave reads only its own staged cols): the
        // compiler's lgkmcnt covers the hp reads below.

        // ---- partials: 4 rows x 4 cols, k-window 32; h reads are 2-addr broadcasts
        float aa0=0.f,aa1=0.f,aa2=0.f,aa3=0.f;
        float ab0=0.f,ab1=0.f,ab2=0.f,ab3=0.f;
        float ac0=0.f,ac1=0.f,ac2=0.f,ac3=0.f;
        float ad0=0.f,ad1=0.f,ad2=0.f,ad3=0.f;

#define FMA4(ACC, WV, HV) \
        ACC = fmaf(WV.x, HV.x, ACC); ACC = fmaf(WV.y, HV.y, ACC); \
        ACC = fmaf(WV.z, HV.z, ACC); ACC = fmaf(WV.w, HV.w, ACC);
#define ROW(B) { \
        const float4* hr = hp4 + (B)*128 + kg*8; \
        const float4 h0=hr[0],h1=hr[1],h2=hr[2],h3=hr[3]; \
        const float4 h4=hr[4],h5=hr[5],h6=hr[6],h7=hr[7]; \
        FMA4(aa##B, wa0,h0) FMA4(aa##B, wa1,h1) FMA4(aa##B, wa2,h2) FMA4(aa##B, wa3,h3) \
        FMA4(aa##B, wa4,h4) FMA4(aa##B, wa5,h5) FMA4(aa##B, wa6,h6) FMA4(aa##B, wa7,h7) \
        FMA4(ab##B, wb0,h0) FMA4(ab##B, wb1,h1) FMA4(ab##B, wb2,h2) FMA4(ab##B, wb3,h3) \
        FMA4(ab##B, wb4,h4) FMA4(ab##B, wb5,h5) FMA4(ab##B, wb6,h6) FMA4(ab##B, wb7,h7) \
        FMA4(ac##B, wc0,h0) FMA4(ac##B, wc1,h1) FMA4(ac##B, wc2,h2) FMA4(ac##B, wc3,h3) \
        FMA4(ac##B, wc4,h4) FMA4(ac##B, wc5,h5) FMA4(ac##B, wc6,h6) FMA4(ac##B, wc7,h7) \
        FMA4(ad##B, wd0,h0) FMA4(ad##B, wd1,h1) FMA4(ad##B, wd2,h2) FMA4(ad##B, wd3,h3) \
        FMA4(ad##B, wd4,h4) FMA4(ad##B, wd5,h5) FMA4(ad##B, wd6,h6) FMA4(ad##B, wd7,h7) }

        ROW(0) __builtin_amdgcn_sched_barrier(0);
        ROW(1) __builtin_amdgcn_sched_barrier(0);
        ROW(2) __builtin_amdgcn_sched_barrier(0);
        ROW(3) __builtin_amdgcn_sched_barrier(0);
#undef ROW
#undef FMA4

        // pack: SCALAR layout Pp[kg*512 + row*128 + col]; per store-instr the
        // 64 lanes write 2x32 consecutive floats -> conflict-free
#define PK(B) \
        Pp[kg*512 + (B)*128 + j     ] = aa##B; \
        Pp[kg*512 + (B)*128 + j + 32] = ab##B; \
        Pp[kg*512 + (B)*128 + j + 64] = ac##B; \
        Pp[kg*512 + (B)*128 + j + 96] = ad##B;
        PK(0) PK(1) PK(2) PK(3)
#undef PK
        __syncthreads();                 // B: all partials ready
        // (no barrier C: Pp(t+2) WAR is covered by B(t+1); hp is wave-private;
        //  hbufU WAR is covered by the sibling-B dependency chain.)

        // ---- reduce: ALL 512 threads, one output each: row=tid>>7, col=tid&127
        //      (addr identity: row*128+col == tid). 16 stride-1 scalar reads,
        //      1 tanh, ONE self-validating 8B publish. No drain, no flag.
        {
            const int row = tid >> 7;
            const int col = tid & 127;
            float s = Pp[tid];
            #pragma unroll
            for (int kk = 1; kk < 16; ++kk) s += Pp[kk * 512 + tid];
            const float xv = xall[t * MB + row];
            s = tanhf(s + xv * wih_s[col] + bias_s[col]);
            const ull pub = ((ull)(uint32)(t + 1) << 32) | (ull)__float_as_uint(s);
            AS(&hbufU[(size_t)(p ^ 1) * BATCH * HH
                      + (size_t)(bbase + row) * HH + jbase + col], pub);
        }
    }
}

__global__ __launch_bounds__(256) void rnn_tail_kernel(
    const ull* __restrict__ hfinU,    // final h in buf 0 (TT even), (tag|bits)
    const float* __restrict__ lin_W, const float* __restrict__ lin_b,
    const int* __restrict__ y, float* __restrict__ out)
{
    __shared__ float redf[256];
    __shared__ int   redi[256];
    const int b = threadIdx.x;
    const ull* hrow = hfinU + (size_t)b * HH;

    float acc[NCLS];
    #pragma unroll
    for (int c = 0; c < NCLS; ++c) acc[c] = lin_b[c];
    // k-outer: h read ONCE; per-class add order identical to the original
    // (acc[c] += h0*w.x + h1*w.y + h2*w.z + h3*w.w, k ascending) -> bit-exact.
    for (int k = 0; k < HH; k += 4) {
        const float h0 = __uint_as_float((uint32)hrow[k + 0]);
        const float h1 = __uint_as_float((uint32)hrow[k + 1]);
        const float h2 = __uint_as_float((uint32)hrow[k + 2]);
        const float h3 = __uint_as_float((uint32)hrow[k + 3]);
        #pragma unroll
        for (int c = 0; c < NCLS; ++c) {
            const float4 wv = *(const float4*)(lin_W + (size_t)c * HH + k);
            acc[c] += h0 * wv.x + h1 * wv.y + h2 * wv.z + h3 * wv.w;
        }
    }
    int am = 0; float m = acc[0];
    #pragma unroll
    for (int c = 1; c < NCLS; ++c) if (acc[c] > m) { m = acc[c]; am = c; } // first-max
    float sum = 0.0f;
    #pragma unroll
    for (int c = 0; c < NCLS; ++c) sum += expf(acc[c] - m);
    const float lse = m + logf(sum);
    const int yy = y[b];
    redf[b] = lse - acc[yy];
    redi[b] = (am == yy) ? 1 : 0;
    __syncthreads();
    for (int s2 = 128; s2 > 0; s2 >>= 1) {
        if (b < s2) { redf[b] += redf[b + s2]; redi[b] += redi[b + s2]; }
        __syncthreads();
    }
    if (b == 0) {
        out[0] = redf[0] / (float)BATCH;  // loss
        out[1] = (float)redi[0];          // correct count
    }
}

extern "C" void kernel_launch(void* const* d_in, const int* in_sizes, int n_in,
                              void* d_out, int out_size, void* d_ws, size_t ws_size,
                              hipStream_t stream) {
    const float* inputs = (const float*)d_in[0];
    const int*   y      = (const int*)  d_in[1];
    const int*   order  = (const int*)  d_in[2];
    const float* W_ih   = (const float*)d_in[3];
    const float* b_ih   = (const float*)d_in[4];
    const float* W_hh   = (const float*)d_in[5];
    const float* b_hh   = (const float*)d_in[6];
    const float* lin_W  = (const float*)d_in[7];
    const float* lin_b  = (const float*)d_in[8];
    float* out = (float*)d_out;

    ull* hbufU = (ull*)((char*)d_ws + 8192);

    // zero tags (and values) — REQUIRED for bench re-runs (stale tags >= t
    // would admit stale h). 2 MB, ~1 us.
    hipMemsetAsync(hbufU, 0, (size_t)2 * BATCH * HH * sizeof(ull), stream);

    void* args[] = {(void*)&inputs, (void*)&order, (void*)&W_ih, (void*)&b_ih,
                    (void*)&W_hh, (void*)&b_hh, (void*)&hbufU};
    hipError_t err = hipLaunchCooperativeKernel((void*)rnn_main_kernel,
                                                dim3(NB * NJ), dim3(NT), args, 0, stream);
    if (err != hipSuccess) {
        hipLaunchKernelGGL(rnn_main_kernel, dim3(NB * NJ), dim3(NT), 0, stream,
                           inputs, order, W_ih, b_ih, W_hh, b_hh, hbufU);
    }

    hipLaunchKernelGGL(rnn_tail_kernel, dim3(1), dim3(256), 0, stream,
                       hbufU, lin_W, lin_b, y, out);
}

// Round 14
// 2244.658 us; speedup vs baseline: 1.0203x; 1.0203x over previous
//
#include <hip/hip_runtime.h>
#include <math.h>

#define BATCH 256
#define TT    784
#define HH    512
#define NCLS  10

#define NB 64          // batch groups
#define NJ 4           // blocks per group; block owns 128 cols
#define MB 4           // batch rows per group
#define HJ 128         // output cols per block
#define NT 512         // threads per block (8 waves, 2/SIMD)

typedef unsigned long long ull;
typedef unsigned int uint32;

#define AL(p)    __hip_atomic_load((p), __ATOMIC_RELAXED, __HIP_MEMORY_SCOPE_AGENT)
#define AS(p, v) __hip_atomic_store((p), (v), __ATOMIC_RELAXED, __HIP_MEMORY_SCOPE_AGENT)

// R0-R13 LESSONS (journal):
//  * R12 (2023 us) = backbone: self-validating (value,tag) 8B publishes
//    (killed drain+flag round-trips, -26%), all-thread scalar reduce,
//    own-slice LDS shortcut + barrier C.
//  * R13 regression (+267 us): routing the OWN-block slice through an L2
//    poll puts a publish->L2->detect round-trip in the self-loop. Rule
//    (confirmed twice, R7+R13): own-slice stays on-CU via LDS + barrier C.
//  * VALUBusy on gfx950 is ~2x inflated (gfx94x SIMD-16 formula): R12's
//    "80%" is ~36% real; ~3950 cyc/step is correlated both-wave stall
//    (poll L2 latency, barrier skew, LDS latency).
//  * THIS ROUND (two order-preserving trims): (1) software-pipelined poll —
//    pre-issue next step's 4 tag-words before barrier C (loads fly during
//    the barrier), check carried values first next step; saves one L2
//    round-trip when fresh. (2) drop the R2-era sched_barrier(0)s between
//    ROWs — they blocked cross-row ds_read prefetch; FP order is dep-fixed
//    so results stay bit-identical (argmax-sensitive outputs: never reorder
//    summation).
//  * R10 coherence rule stands: cross-CU reads MUST bypass L1 (AL = sc0).
//
// d_ws layout:
//   [8192, 8192+2MB) : hbufU ull[2][BATCH][HH] — (tag<<32)|float_bits,
//                      agent-relaxed. Tags zeroed by hipMemsetAsync each
//                      launch (resets between bench iterations).

// Opaque register pin: weights become outputs of a volatile asm — cannot be
// rematerialized or sunk into the loop.
#define PIN(V) asm volatile("" : "+v"((V).x), "+v"((V).y), "+v"((V).z), "+v"((V).w))

__global__ __launch_bounds__(NT)
__attribute__((amdgpu_waves_per_eu(2, 2)))
void rnn_main_kernel(
    const float* __restrict__ inputs, const int* __restrict__ order,
    const float* __restrict__ W_ih, const float* __restrict__ b_ih,
    const float* __restrict__ W_hh, const float* __restrict__ b_hh,
    ull* __restrict__ hbufU)
{
    __shared__ float hp[MB * HH];            // 8 KB : h tile (canonical col layout)
    __shared__ float pbuf[16 * MB * HJ];     // 32 KB: partials, SCALAR [kk][row][col]
    __shared__ float xall[TT * MB];          // 12.25 KB: inputs[b][order[t]]
    __shared__ float wih_s[HJ];
    __shared__ float bias_s[HJ];

    const int tid   = threadIdx.x;
    const int blk   = blockIdx.x;
    const int bb    = blk & (NB - 1);        // group; members blk=bb+64g -> same XCD under %8
    const int jjg   = blk >> 6;              // producer id 0..3: cols [jjg*128, +128)
    const int jbase = jjg * HJ;
    const int bbase = bb * MB;
    const int j   = tid & 31;                // base col lane: cols {j, j+32, j+64, j+96}
    const int kg  = tid >> 5;                // k-chunk 0..15 (32 k each)
    const int w   = tid >> 6;                // wave: k-window [64w,+64), producer g=w>>1
    const int g   = w >> 1;
    const int l   = tid & 63;
    const int isCons = (g != jjg);           // this wave polls a remote producer

    // ---- W_hh slice in NAMED registers: 4 cols x 32 k = 32 float4
    //      (live in the unified VGPR/AGPR file; VALU reads them directly)
    const float4* wpa = (const float4*)(W_hh + (size_t)(jbase + j +  0) * HH + kg * 32);
    const float4* wpb = (const float4*)(W_hh + (size_t)(jbase + j + 32) * HH + kg * 32);
    const float4* wpc = (const float4*)(W_hh + (size_t)(jbase + j + 64) * HH + kg * 32);
    const float4* wpd = (const float4*)(W_hh + (size_t)(jbase + j + 96) * HH + kg * 32);
    float4 wa0 = wpa[0], wa1 = wpa[1], wa2 = wpa[2], wa3 = wpa[3];
    float4 wa4 = wpa[4], wa5 = wpa[5], wa6 = wpa[6], wa7 = wpa[7];
    float4 wb0 = wpb[0], wb1 = wpb[1], wb2 = wpb[2], wb3 = wpb[3];
    float4 wb4 = wpb[4], wb5 = wpb[5], wb6 = wpb[6], wb7 = wpb[7];
    float4 wc0 = wpc[0], wc1 = wpc[1], wc2 = wpc[2], wc3 = wpc[3];
    float4 wc4 = wpc[4], wc5 = wpc[5], wc6 = wpc[6], wc7 = wpc[7];
    float4 wd0 = wpd[0], wd1 = wpd[1], wd2 = wpd[2], wd3 = wpd[3];
    float4 wd4 = wpd[4], wd5 = wpd[5], wd6 = wpd[6], wd7 = wpd[7];

    PIN(wa0); PIN(wa1); PIN(wa2); PIN(wa3);
    PIN(wa4); PIN(wa5); PIN(wa6); PIN(wa7);
    PIN(wb0); PIN(wb1); PIN(wb2); PIN(wb3);
    PIN(wb4); PIN(wb5); PIN(wb6); PIN(wb7);
    PIN(wc0); PIN(wc1); PIN(wc2); PIN(wc3);
    PIN(wc4); PIN(wc5); PIN(wc6); PIN(wc7);
    PIN(wd0); PIN(wd1); PIN(wd2); PIN(wd3);
    PIN(wd4); PIN(wd5); PIN(wd6); PIN(wd7);

    if (tid < HJ) {
        wih_s[tid]  = W_ih[jbase + tid];
        bias_s[tid] = b_ih[jbase + tid] + b_hh[jbase + tid];
    }
    for (int idx = tid; idx < TT * MB; idx += NT) {
        const int t = idx >> 2;
        const int b = idx & (MB - 1);
        xall[idx] = inputs[(size_t)(bbase + b) * TT + order[t]];
    }
    ((float4*)hp)[tid] = make_float4(0.f, 0.f, 0.f, 0.f);   // h_0 = 0 (8 KB)
    __syncthreads();

    const float4* hp4 = (const float4*)hp;

    // per-lane poll addresses in both parity buffers (this wave's 4 rows at
    // col w*64+l)
    const ull* src0 = hbufU + (size_t)bbase * HH + w * 64 + l;           // buf 0
    const ull* src1 = src0 + (size_t)BATCH * HH;                         // buf 1
    // carried pre-issued tag-words (stale-init -> first real poll loops)
    ull c0 = 0, c1 = 0, c2 = 0, c3 = 0;

    for (int t = 0; t < TT; ++t) {
        const int p = t & 1;

        // ---- per-wave gate+stage: check the CARRIED pre-issued words first
        //      (issued just before last step's barrier C — their L2 latency
        //      hid under the barrier). Loop-reload only if stale.
        if (t > 0 && isCons) {
            const uint32 tg = (uint32)t;
            const ull* src = p ? src1 : src0;
            ull u0 = c0, u1 = c1, u2 = c2, u3 = c3;
            for (;;) {
                const int ok = ((uint32)(u0 >> 32) >= tg) & ((uint32)(u1 >> 32) >= tg)
                             & ((uint32)(u2 >> 32) >= tg) & ((uint32)(u3 >> 32) >= tg);
                if (__all(ok)) break;
                u0 = AL(src);            u1 = AL(src + HH);
                u2 = AL(src + 2 * HH);   u3 = AL(src + 3 * HH);
            }
            hp[0 * HH + w * 64 + l] = __uint_as_float((uint32)u0);
            hp[1 * HH + w * 64 + l] = __uint_as_float((uint32)u1);
            hp[2 * HH + w * 64 + l] = __uint_as_float((uint32)u2);
            hp[3 * HH + w * 64 + l] = __uint_as_float((uint32)u3);
        }
        // intra-wave LDS RAW: compiler's lgkmcnt covers the hp reads below.

        // ---- partials: 4 rows x 4 cols, k-window 32; h reads are 2-addr
        //      broadcasts. No sched_barriers: let the scheduler prefetch the
        //      next row's ds_reads under this row's FMA chain (FP order is
        //      dependency-fixed -> bit-identical).
        float aa0=0.f,aa1=0.f,aa2=0.f,aa3=0.f;
        float ab0=0.f,ab1=0.f,ab2=0.f,ab3=0.f;
        float ac0=0.f,ac1=0.f,ac2=0.f,ac3=0.f;
        float ad0=0.f,ad1=0.f,ad2=0.f,ad3=0.f;

#define FMA4(ACC, WV, HV) \
        ACC = fmaf(WV.x, HV.x, ACC); ACC = fmaf(WV.y, HV.y, ACC); \
        ACC = fmaf(WV.z, HV.z, ACC); ACC = fmaf(WV.w, HV.w, ACC);
#define ROW(B) { \
        const float4* hr = hp4 + (B)*128 + kg*8; \
        const float4 h0=hr[0],h1=hr[1],h2=hr[2],h3=hr[3]; \
        const float4 h4=hr[4],h5=hr[5],h6=hr[6],h7=hr[7]; \
        FMA4(aa##B, wa0,h0) FMA4(aa##B, wa1,h1) FMA4(aa##B, wa2,h2) FMA4(aa##B, wa3,h3) \
        FMA4(aa##B, wa4,h4) FMA4(aa##B, wa5,h5) FMA4(aa##B, wa6,h6) FMA4(aa##B, wa7,h7) \
        FMA4(ab##B, wb0,h0) FMA4(ab##B, wb1,h1) FMA4(ab##B, wb2,h2) FMA4(ab##B, wb3,h3) \
        FMA4(ab##B, wb4,h4) FMA4(ab##B, wb5,h5) FMA4(ab##B, wb6,h6) FMA4(ab##B, wb7,h7) \
        FMA4(ac##B, wc0,h0) FMA4(ac##B, wc1,h1) FMA4(ac##B, wc2,h2) FMA4(ac##B, wc3,h3) \
        FMA4(ac##B, wc4,h4) FMA4(ac##B, wc5,h5) FMA4(ac##B, wc6,h6) FMA4(ac##B, wc7,h7) \
        FMA4(ad##B, wd0,h0) FMA4(ad##B, wd1,h1) FMA4(ad##B, wd2,h2) FMA4(ad##B, wd3,h3) \
        FMA4(ad##B, wd4,h4) FMA4(ad##B, wd5,h5) FMA4(ad##B, wd6,h6) FMA4(ad##B, wd7,h7) }

        ROW(0) ROW(1) ROW(2) ROW(3)
#undef ROW
#undef FMA4

        // pack: SCALAR layout pbuf[kg*512 + row*128 + col]; per store-instr the
        // 64 lanes write 2x32 consecutive floats -> conflict-free
#define PK(B) \
        pbuf[kg*512 + (B)*128 + j     ] = aa##B; \
        pbuf[kg*512 + (B)*128 + j + 32] = ab##B; \
        pbuf[kg*512 + (B)*128 + j + 64] = ac##B; \
        pbuf[kg*512 + (B)*128 + j + 96] = ad##B;
        PK(0) PK(1) PK(2) PK(3)
#undef PK
        __syncthreads();                 // B: all partials ready

        // ---- reduce: ALL 512 threads, one output each: row=tid>>7, col=tid&127
        //      (addr identity: row*128+col == tid). 16 stride-1 scalar reads,
        //      1 tanh, ONE self-validating 8B publish. No drain, no flag.
        {
            const int row = tid >> 7;
            const int col = tid & 127;
            float s = pbuf[tid];
            #pragma unroll
            for (int kk = 1; kk < 16; ++kk) s += pbuf[kk * 512 + tid];
            const float xv = xall[t * MB + row];
            s = tanhf(s + xv * wih_s[col] + bias_s[col]);
            const ull pub = ((ull)(uint32)(t + 1) << 32) | (ull)__float_as_uint(s);
            AS(&hbufU[(size_t)(p ^ 1) * BATCH * HH
                      + (size_t)(bbase + row) * HH + jbase + col], pub);
            // own-slice shortcut for own-block consumer waves next step
            hp[row * HH + jbase + col] = s;
        }

        // ---- pre-issue next step's tag-words (buffer p^1): their L2 round
        //      trip overlaps the barrier-C wait + next step's FMA lead-in.
        if (isCons && t + 1 < TT) {
            const ull* sn = p ? src0 : src1;    // buffer (t+1)&1 == p^1
            c0 = AL(sn);            c1 = AL(sn + HH);
            c2 = AL(sn + 2 * HH);   c3 = AL(sn + 3 * HH);
        }
        __syncthreads();                 // C: pbuf WAR + own-slice visible
    }
}

__global__ __launch_bounds__(256) void rnn_tail_kernel(
    const ull* __restrict__ hfinU,    // final h in buf 0 (TT even), (tag|bits)
    const float* __restrict__ lin_W, const float* __restrict__ lin_b,
    const int* __restrict__ y, float* __restrict__ out)
{
    __shared__ float redf[256];
    __shared__ int   redi[256];
    const int b = threadIdx.x;
    const ull* hrow = hfinU + (size_t)b * HH;

    float acc[NCLS];
    #pragma unroll
    for (int c = 0; c < NCLS; ++c) acc[c] = lin_b[c];
    // k-outer: h read ONCE; per-class add order identical to the original
    // (acc[c] += h0*w.x + h1*w.y + h2*w.z + h3*w.w, k ascending) -> bit-exact.
    for (int k = 0; k < HH; k += 4) {
        const float h0 = __uint_as_float((uint32)hrow[k + 0]);
        const float h1 = __uint_as_float((uint32)hrow[k + 1]);
        const float h2 = __uint_as_float((uint32)hrow[k + 2]);
        const float h3 = __uint_as_float((uint32)hrow[k + 3]);
        #pragma unroll
        for (int c = 0; c < NCLS; ++c) {
            const float4 wv = *(const float4*)(lin_W + (size_t)c * HH + k);
            acc[c] += h0 * wv.x + h1 * wv.y + h2 * wv.z + h3 * wv.w;
        }
    }
    int am = 0; float m = acc[0];
    #pragma unroll
    for (int c = 1; c < NCLS; ++c) if (acc[c] > m) { m = acc[c]; am = c; } // first-max
    float sum = 0.0f;
    #pragma unroll
    for (int c = 0; c < NCLS; ++c) sum += expf(acc[c] - m);
    const float lse = m + logf(sum);
    const int yy = y[b];
    redf[b] = lse - acc[yy];
    redi[b] = (am == yy) ? 1 : 0;
    __syncthreads();
    for (int s2 = 128; s2 > 0; s2 >>= 1) {
        if (b < s2) { redf[b] += redf[b + s2]; redi[b] += redi[b + s2]; }
        __syncthreads();
    }
    if (b == 0) {
        out[0] = redf[0] / (float)BATCH;  // loss
        out[1] = (float)redi[0];          // correct count
    }
}

extern "C" void kernel_launch(void* const* d_in, const int* in_sizes, int n_in,
                              void* d_out, int out_size, void* d_ws, size_t ws_size,
                              hipStream_t stream) {
    const float* inputs = (const float*)d_in[0];
    const int*   y      = (const int*)  d_in[1];
    const int*   order  = (const int*)  d_in[2];
    const float* W_ih   = (const float*)d_in[3];
    const float* b_ih   = (const float*)d_in[4];
    const float* W_hh   = (const float*)d_in[5];
    const float* b_hh   = (const float*)d_in[6];
    const float* lin_W  = (const float*)d_in[7];
    const float* lin_b  = (const float*)d_in[8];
    float* out = (float*)d_out;

    ull* hbufU = (ull*)((char*)d_ws + 8192);

    // zero tags (and values) — REQUIRED for bench re-runs (stale tags >= t
    // would admit stale h). 2 MB, ~1 us.
    hipMemsetAsync(hbufU, 0, (size_t)2 * BATCH * HH * sizeof(ull), stream);

    void* args[] = {(void*)&inputs, (void*)&order, (void*)&W_ih, (void*)&b_ih,
                    (void*)&W_hh, (void*)&b_hh, (void*)&hbufU};
    hipError_t err = hipLaunchCooperativeKernel((void*)rnn_main_kernel,
                                                dim3(NB * NJ), dim3(NT), args, 0, stream);
    if (err != hipSuccess) {
        hipLaunchKernelGGL(rnn_main_kernel, dim3(NB * NJ), dim3(NT), 0, stream,
                           inputs, order, W_ih, b_ih, W_hh, b_hh, hbufU);
    }

    hipLaunchKernelGGL(rnn_tail_kernel, dim3(1), dim3(256), 0, stream,
                       hbufU, lin_W, lin_b, y, out);
}

// Round 15
// 2026.730 us; speedup vs baseline: 1.1300x; 1.1075x over previous
//
#include <hip/hip_runtime.h>
#include <math.h>

#define BATCH 256
#define TT    784
#define HH    512
#define NCLS  10

#define NB 64          // batch groups
#define NJ 4           // blocks per group; block owns 128 cols
#define MB 4           // batch rows per group
#define HJ 128         // output cols per block
#define NT 512         // threads per block (8 waves, 2/SIMD)

typedef unsigned long long ull;
typedef unsigned int uint32;

#define AL(p)    __hip_atomic_load((p), __ATOMIC_RELAXED, __HIP_MEMORY_SCOPE_AGENT)
#define AS(p, v) __hip_atomic_store((p), (v), __ATOMIC_RELAXED, __HIP_MEMORY_SCOPE_AGENT)

// R0-R14 LESSONS (journal) — final state = R12 backbone (best: 2023 us):
//  * Self-validating (value,tag) 8B publishes (R12, -26%): producer stores
//    (tag<<32)|bits, no vmcnt drain, no flag; consumer polls its OWN words,
//    on tag-match the value is already in-register. Killed 2 of 3 L2
//    round-trips per step.
//  * All-thread scalar reduce + conflict-free scalar pbuf (R8, -12%).
//  * Own-slice must stay on-CU via LDS + barrier C (R7/R13: routing it
//    through L2 costs +250-1500 us — it's the self-dependency loop).
//  * Poll pre-issue before barrier C is a LOSS (R14: carried words race the
//    producers' publish, arrive stale, +10% FETCH and +222 us).
//  * Occupancy: 1 block/CU, 2 waves/SIMD is optimal (R6: 4 waves/SIMD =
//    scratch disaster; R9: 2 blocks/CU = +32%). Unified VGPR+AGPR file
//    (~512/SIMD) keeps the 128 weight floats resident at 2 waves/SIMD.
//  * Cross-CU reads MUST bypass L1 (sc0) — R10's absmax=8 failure was a
//    plain cached global_load_lds hitting stale L1.
//  * VALUBusy on gfx950 is ~2x inflated (gfx94x SIMD-16 formula).
//  * Remaining ~6190 cyc/step: FMA issue 2048 + LDS pipe ~1200 + publish->
//    detect ~400 (irreducible data dep) + barrier skew. No single large
//    removable term remains; 3 consecutive refinements regressed.
//
// d_ws layout:
//   [8192, 8192+2MB) : hbufU ull[2][BATCH][HH] — (tag<<32)|float_bits,
//                      agent-relaxed. Tags zeroed by hipMemsetAsync each
//                      launch (resets between bench iterations).

// Opaque register pin: weights become outputs of a volatile asm — cannot be
// rematerialized or sunk into the loop.
#define PIN(V) asm volatile("" : "+v"((V).x), "+v"((V).y), "+v"((V).z), "+v"((V).w))

__global__ __launch_bounds__(NT)
__attribute__((amdgpu_waves_per_eu(2, 2)))
void rnn_main_kernel(
    const float* __restrict__ inputs, const int* __restrict__ order,
    const float* __restrict__ W_ih, const float* __restrict__ b_ih,
    const float* __restrict__ W_hh, const float* __restrict__ b_hh,
    ull* __restrict__ hbufU)
{
    __shared__ float hp[MB * HH];            // 8 KB : h tile (canonical col layout)
    __shared__ float pbuf[16 * MB * HJ];     // 32 KB: partials, SCALAR [kk][row][col]
    __shared__ float xall[TT * MB];          // 12.25 KB: inputs[b][order[t]]
    __shared__ float wih_s[HJ];
    __shared__ float bias_s[HJ];

    const int tid   = threadIdx.x;
    const int blk   = blockIdx.x;
    const int bb    = blk & (NB - 1);        // group; members blk=bb+64g -> same XCD under %8
    const int jjg   = blk >> 6;              // producer id 0..3: cols [jjg*128, +128)
    const int jbase = jjg * HJ;
    const int bbase = bb * MB;
    const int j   = tid & 31;                // base col lane: cols {j, j+32, j+64, j+96}
    const int kg  = tid >> 5;                // k-chunk 0..15 (32 k each)
    const int w   = tid >> 6;                // wave: k-window [64w,+64), producer g=w>>1
    const int g   = w >> 1;
    const int l   = tid & 63;

    // ---- W_hh slice in NAMED registers: 4 cols x 32 k = 32 float4
    //      (live in the unified VGPR/AGPR file; VALU reads them directly)
    const float4* wpa = (const float4*)(W_hh + (size_t)(jbase + j +  0) * HH + kg * 32);
    const float4* wpb = (const float4*)(W_hh + (size_t)(jbase + j + 32) * HH + kg * 32);
    const float4* wpc = (const float4*)(W_hh + (size_t)(jbase + j + 64) * HH + kg * 32);
    const float4* wpd = (const float4*)(W_hh + (size_t)(jbase + j + 96) * HH + kg * 32);
    float4 wa0 = wpa[0], wa1 = wpa[1], wa2 = wpa[2], wa3 = wpa[3];
    float4 wa4 = wpa[4], wa5 = wpa[5], wa6 = wpa[6], wa7 = wpa[7];
    float4 wb0 = wpb[0], wb1 = wpb[1], wb2 = wpb[2], wb3 = wpb[3];
    float4 wb4 = wpb[4], wb5 = wpb[5], wb6 = wpb[6], wb7 = wpb[7];
    float4 wc0 = wpc[0], wc1 = wpc[1], wc2 = wpc[2], wc3 = wpc[3];
    float4 wc4 = wpc[4], wc5 = wpc[5], wc6 = wpc[6], wc7 = wpc[7];
    float4 wd0 = wpd[0], wd1 = wpd[1], wd2 = wpd[2], wd3 = wpd[3];
    float4 wd4 = wpd[4], wd5 = wpd[5], wd6 = wpd[6], wd7 = wpd[7];

    PIN(wa0); PIN(wa1); PIN(wa2); PIN(wa3);
    PIN(wa4); PIN(wa5); PIN(wa6); PIN(wa7);
    PIN(wb0); PIN(wb1); PIN(wb2); PIN(wb3);
    PIN(wb4); PIN(wb5); PIN(wb6); PIN(wb7);
    PIN(wc0); PIN(wc1); PIN(wc2); PIN(wc3);
    PIN(wc4); PIN(wc5); PIN(wc6); PIN(wc7);
    PIN(wd0); PIN(wd1); PIN(wd2); PIN(wd3);
    PIN(wd4); PIN(wd5); PIN(wd6); PIN(wd7);

    if (tid < HJ) {
        wih_s[tid]  = W_ih[jbase + tid];
        bias_s[tid] = b_ih[jbase + tid] + b_hh[jbase + tid];
    }
    for (int idx = tid; idx < TT * MB; idx += NT) {
        const int t = idx >> 2;
        const int b = idx & (MB - 1);
        xall[idx] = inputs[(size_t)(bbase + b) * TT + order[t]];
    }
    ((float4*)hp)[tid] = make_float4(0.f, 0.f, 0.f, 0.f);   // h_0 = 0 (8 KB)
    __syncthreads();

    const float4* hp4 = (const float4*)hp;

    for (int t = 0; t < TT; ++t) {
        const int p = t & 1;

        // ---- per-wave gate+stage fused: each lane polls ITS OWN 4 pair-words
        //      (one per batch row at col w*64+l). Tag match => value already
        //      in-register; 4 ds_writes finish the stage. No flag, no fetch.
        if (t > 0 && g != jjg) {
            const uint32 tg = (uint32)t;
            const ull* src = hbufU + (size_t)p * BATCH * HH
                             + (size_t)bbase * HH + w * 64 + l;
            ull u0, u1, u2, u3;
            for (;;) {
                u0 = AL(src);            u1 = AL(src + HH);
                u2 = AL(src + 2 * HH);   u3 = AL(src + 3 * HH);
                const int ok = ((uint32)(u0 >> 32) >= tg) & ((uint32)(u1 >> 32) >= tg)
                             & ((uint32)(u2 >> 32) >= tg) & ((uint32)(u3 >> 32) >= tg);
                if (__all(ok)) break;
            }
            hp[0 * HH + w * 64 + l] = __uint_as_float((uint32)u0);
            hp[1 * HH + w * 64 + l] = __uint_as_float((uint32)u1);
            hp[2 * HH + w * 64 + l] = __uint_as_float((uint32)u2);
            hp[3 * HH + w * 64 + l] = __uint_as_float((uint32)u3);
        }
        // intra-wave LDS RAW: compiler's lgkmcnt covers the hp reads below.

        // ---- partials: 4 rows x 4 cols, k-window 32; h reads are 2-addr broadcasts
        float aa0=0.f,aa1=0.f,aa2=0.f,aa3=0.f;
        float ab0=0.f,ab1=0.f,ab2=0.f,ab3=0.f;
        float ac0=0.f,ac1=0.f,ac2=0.f,ac3=0.f;
        float ad0=0.f,ad1=0.f,ad2=0.f,ad3=0.f;

#define FMA4(ACC, WV, HV) \
        ACC = fmaf(WV.x, HV.x, ACC); ACC = fmaf(WV.y, HV.y, ACC); \
        ACC = fmaf(WV.z, HV.z, ACC); ACC = fmaf(WV.w, HV.w, ACC);
#define ROW(B) { \
        const float4* hr = hp4 + (B)*128 + kg*8; \
        const float4 h0=hr[0],h1=hr[1],h2=hr[2],h3=hr[3]; \
        const float4 h4=hr[4],h5=hr[5],h6=hr[6],h7=hr[7]; \
        FMA4(aa##B, wa0,h0) FMA4(aa##B, wa1,h1) FMA4(aa##B, wa2,h2) FMA4(aa##B, wa3,h3) \
        FMA4(aa##B, wa4,h4) FMA4(aa##B, wa5,h5) FMA4(aa##B, wa6,h6) FMA4(aa##B, wa7,h7) \
        FMA4(ab##B, wb0,h0) FMA4(ab##B, wb1,h1) FMA4(ab##B, wb2,h2) FMA4(ab##B, wb3,h3) \
        FMA4(ab##B, wb4,h4) FMA4(ab##B, wb5,h5) FMA4(ab##B, wb6,h6) FMA4(ab##B, wb7,h7) \
        FMA4(ac##B, wc0,h0) FMA4(ac##B, wc1,h1) FMA4(ac##B, wc2,h2) FMA4(ac##B, wc3,h3) \
        FMA4(ac##B, wc4,h4) FMA4(ac##B, wc5,h5) FMA4(ac##B, wc6,h6) FMA4(ac##B, wc7,h7) \
        FMA4(ad##B, wd0,h0) FMA4(ad##B, wd1,h1) FMA4(ad##B, wd2,h2) FMA4(ad##B, wd3,h3) \
        FMA4(ad##B, wd4,h4) FMA4(ad##B, wd5,h5) FMA4(ad##B, wd6,h6) FMA4(ad##B, wd7,h7) }

        ROW(0) __builtin_amdgcn_sched_barrier(0);
        ROW(1) __builtin_amdgcn_sched_barrier(0);
        ROW(2) __builtin_amdgcn_sched_barrier(0);
        ROW(3) __builtin_amdgcn_sched_barrier(0);
#undef ROW
#undef FMA4

        // pack: SCALAR layout pbuf[kg*512 + row*128 + col]; per store-instr the
        // 64 lanes write 2x32 consecutive floats -> conflict-free
#define PK(B) \
        pbuf[kg*512 + (B)*128 + j     ] = aa##B; \
        pbuf[kg*512 + (B)*128 + j + 32] = ab##B; \
        pbuf[kg*512 + (B)*128 + j + 64] = ac##B; \
        pbuf[kg*512 + (B)*128 + j + 96] = ad##B;
        PK(0) PK(1) PK(2) PK(3)
#undef PK
        __syncthreads();                 // B: all partials ready

        // ---- reduce: ALL 512 threads, one output each: row=tid>>7, col=tid&127
        //      (addr identity: row*128+col == tid). 16 stride-1 scalar reads,
        //      1 tanh, ONE self-validating 8B publish. No drain, no flag.
        {
            const int row = tid >> 7;
            const int col = tid & 127;
            float s = pbuf[tid];
            #pragma unroll
            for (int kk = 1; kk < 16; ++kk) s += pbuf[kk * 512 + tid];
            const float xv = xall[t * MB + row];
            s = tanhf(s + xv * wih_s[col] + bias_s[col]);
            const ull pub = ((ull)(uint32)(t + 1) << 32) | (ull)__float_as_uint(s);
            AS(&hbufU[(size_t)(p ^ 1) * BATCH * HH
                      + (size_t)(bbase + row) * HH + jbase + col], pub);
            // own-slice shortcut for own-block consumer waves next step
            hp[row * HH + jbase + col] = s;
        }
        __syncthreads();                 // C: pbuf WAR + own-slice visible
    }
}

__global__ __launch_bounds__(256) void rnn_tail_kernel(
    const ull* __restrict__ hfinU,    // final h in buf 0 (TT even), (tag|bits)
    const float* __restrict__ lin_W, const float* __restrict__ lin_b,
    const int* __restrict__ y, float* __restrict__ out)
{
    __shared__ float redf[256];
    __shared__ int   redi[256];
    const int b = threadIdx.x;
    const ull* hrow = hfinU + (size_t)b * HH;

    float acc[NCLS];
    #pragma unroll
    for (int c = 0; c < NCLS; ++c) acc[c] = lin_b[c];
    // k-outer: h read ONCE; per-class add order identical to the original
    // (acc[c] += h0*w.x + h1*w.y + h2*w.z + h3*w.w, k ascending) -> bit-exact.
    for (int k = 0; k < HH; k += 4) {
        const float h0 = __uint_as_float((uint32)hrow[k + 0]);
        const float h1 = __uint_as_float((uint32)hrow[k + 1]);
        const float h2 = __uint_as_float((uint32)hrow[k + 2]);
        const float h3 = __uint_as_float((uint32)hrow[k + 3]);
        #pragma unroll
        for (int c = 0; c < NCLS; ++c) {
            const float4 wv = *(const float4*)(lin_W + (size_t)c * HH + k);
            acc[c] += h0 * wv.x + h1 * wv.y + h2 * wv.z + h3 * wv.w;
        }
    }
    int am = 0; float m = acc[0];
    #pragma unroll
    for (int c = 1; c < NCLS; ++c) if (acc[c] > m) { m = acc[c]; am = c; } // first-max
    float sum = 0.0f;
    #pragma unroll
    for (int c = 0; c < NCLS; ++c) sum += expf(acc[c] - m);
    const float lse = m + logf(sum);
    const int yy = y[b];
    redf[b] = lse - acc[yy];
    redi[b] = (am == yy) ? 1 : 0;
    __syncthreads();
    for (int s2 = 128; s2 > 0; s2 >>= 1) {
        if (b < s2) { redf[b] += redf[b + s2]; redi[b] += redi[b + s2]; }
        __syncthreads();
    }
    if (b == 0) {
        out[0] = redf[0] / (float)BATCH;  // loss
        out[1] = (float)redi[0];          // correct count
    }
}

extern "C" void kernel_launch(void* const* d_in, const int* in_sizes, int n_in,
                              void* d_out, int out_size, void* d_ws, size_t ws_size,
                              hipStream_t stream) {
    const float* inputs = (const float*)d_in[0];
    const int*   y      = (const int*)  d_in[1];
    const int*   order  = (const int*)  d_in[2];
    const float* W_ih   = (const float*)d_in[3];
    const float* b_ih   = (const float*)d_in[4];
    const float* W_hh   = (const float*)d_in[5];
    const float* b_hh   = (const float*)d_in[6];
    const float* lin_W  = (const float*)d_in[7];
    const float* lin_b  = (const float*)d_in[8];
    float* out = (float*)d_out;

    ull* hbufU = (ull*)((char*)d_ws + 8192);

    // zero tags (and values) — REQUIRED for bench re-runs (stale tags >= t
    // would admit stale h). 2 MB, ~1 us.
    hipMemsetAsync(hbufU, 0, (size_t)2 * BATCH * HH * sizeof(ull), stream);

    void* args[] = {(void*)&inputs, (void*)&order, (void*)&W_ih, (void*)&b_ih,
                    (void*)&W_hh, (void*)&b_hh, (void*)&hbufU};
    hipError_t err = hipLaunchCooperativeKernel((void*)rnn_main_kernel,
                                                dim3(NB * NJ), dim3(NT), args, 0, stream);
    if (err != hipSuccess) {
        hipLaunchKernelGGL(rnn_main_kernel, dim3(NB * NJ), dim3(NT), 0, stream,
                           inputs, order, W_ih, b_ih, W_hh, b_hh, hbufU);
    }

    hipLaunchKernelGGL(rnn_tail_kernel, dim3(1), dim3(256), 0, stream,
                       hbufU, lin_W, lin_b, y, out);
}